// Round 5
// baseline (454.641 us; speedup 1.0000x reference)
//
#include <hip/hip_runtime.h>

// LIF scan: thread-per-(b,c) chain, 4-way speculative T-split (W=80 warm-up,
// >= R3's validated W=75), U=10 double-buffered prefetch. 4096 waves = 4/SIMD.

constexpr int B = 128;
constexpr int T = 1000;
constexpr int C = 512;
constexpr int NCH = 4;
constexpr int CHUNK = 250;  // stored steps per chunk
constexpr int W = 80;       // warm-up steps for chunks k>0
constexpr int U = 10;       // steps per load batch; 250=25*10, 330=33*10

__global__ __launch_bounds__(256) void lif_kernel(
    const float* __restrict__ x, const float* __restrict__ w_leak,
    float* __restrict__ out) {
#pragma clang fp contract(off)
  const int k = blockIdx.x >> 8;                       // T-chunk: 0..3
  const int gi = ((blockIdx.x & 255) << 8) | threadIdx.x;
  const int b = gi >> 9;          // / C
  const int c = gi & (C - 1);     // % C
  const float decay = 1.0f - w_leak[c];

  const int tb = (k == 0) ? 0 : (k * CHUNK - W);            // load start
  const int nb = (k == 0) ? (CHUNK / U) : ((CHUNK + W) / U); // 25 or 33
  const int nwarm = nb - CHUNK / U;                          // 0 or 8

  const float* xp = x + ((size_t)b * T + tb) * C + c;
  float* op = out + ((size_t)b * T + (size_t)k * CHUNK) * C + c;

  float bufA[U], bufB[U];
  float Vm = 0.0f;

#define LOADB(buf, j)                                                      \
  do {                                                                     \
    const float* p_ = xp + (size_t)(j) * ((size_t)U * C);                  \
    _Pragma("unroll")                                                      \
    for (int u = 0; u < U; ++u) buf[u] = p_[(size_t)u * C];                \
  } while (0)

#define COMPUTEB(buf, j)                                                   \
  do {                                                                     \
    const bool st_ = (j) >= nwarm;   /* uniform per block */               \
    float* q_ = op + (ptrdiff_t)((j) - nwarm) * (U * C);                   \
    _Pragma("unroll")                                                      \
    for (int u = 0; u < U; ++u) {                                          \
      float dv = decay * Vm;               /* one rounding, no FMA */      \
      dv = (Vm < 1.0f) ? dv : 0.0f;        /* hard-reset gate */           \
      float s = buf[u] + dv;               /* one rounding */              \
      Vm = fmaxf(s, 0.0f);                 /* relu */                      \
      if (st_)                                                             \
        __builtin_nontemporal_store((Vm > 1.0f) ? 1.0f : 0.0f,             \
                                    q_ + (size_t)u * C);                   \
    }                                                                      \
  } while (0)

  LOADB(bufA, 0);
  LOADB(bufB, 1);

  int j = 0;
#pragma unroll 1
  for (; j + 2 <= nb; j += 2) {
    COMPUTEB(bufA, j);
    if (j + 2 < nb) LOADB(bufA, j + 2);
    COMPUTEB(bufB, j + 1);
    if (j + 3 < nb) LOADB(bufB, j + 3);
  }
  if (j < nb) COMPUTEB(bufA, j);   // odd-nb tail (nb=25/33 -> last in bufA)

#undef LOADB
#undef COMPUTEB
}

extern "C" void kernel_launch(void* const* d_in, const int* in_sizes, int n_in,
                              void* d_out, int out_size, void* d_ws, size_t ws_size,
                              hipStream_t stream) {
  const float* x = (const float*)d_in[0];
  const float* w = (const float*)d_in[1];
  float* out = (float*)d_out;
  dim3 block(256);
  dim3 grid((B * C) / 256 * NCH);   // 1024 blocks: chunk = bid>>8
  lif_kernel<<<grid, block, 0, stream>>>(x, w, out);
}

// Round 6
// 454.336 us; speedup vs baseline: 1.0007x; 1.0007x over previous
//
#include <hip/hip_runtime.h>

// LIF scan: thread-per-(b,c) chain, 4-way speculative T-split (W=75,
// validated R3/R5). The compiler collapsed every register double-buffer
// (VGPR 24-44 across R2-R5) leaving ~4 loads in flight/wave -> 2.5 TB/s.
// Fix: hand-rolled 25-deep prefetch via asm volatile global_load_dword +
// uniform s_waitcnt vmcnt(24) + sched_barrier(0) (rule #18).
//
// vmcnt correctness: loads/stores interleave 1:1 (dummy stores during
// warm-up keep this uniform). vmcnt retires in order. Slot u's load has
// >=24 vmem ops issued after it at its wait point (24-u refill loads of
// the previous group + 2u store/load pairs of this group; last group:
// 24-u loads + u stores). outstanding<=24 => that load retired.

constexpr int B = 128;
constexpr int T = 1000;
constexpr int C = 512;
constexpr int NCH = 4;
constexpr int CHUNK = 250;  // stored steps per chunk
constexpr int W = 75;       // warm-up steps for chunks k>0
constexpr int D = 25;       // pipeline depth; divides 250 and 325

__global__ __launch_bounds__(256) void lif_kernel(
    const float* __restrict__ x, const float* __restrict__ w_leak,
    float* __restrict__ out, float* __restrict__ ws, int use_ws) {
#pragma clang fp contract(off)
  const int k = blockIdx.x >> 8;                       // T-chunk: 0..3
  const int gi = ((blockIdx.x & 255) << 8) | threadIdx.x;
  const int b = gi >> 9;          // / C
  const int c = gi & (C - 1);     // % C
  const float decay = 1.0f - w_leak[c];

  const int tb = (k == 0) ? 0 : (k * CHUNK - W);
  const int ng = (k == 0) ? (CHUNK / D) : ((CHUNK + W) / D);  // 10 or 13
  const int nwg = ng - CHUNK / D;                             // 0 or 3

  const float* xp = x + ((size_t)b * T + tb) * C + c;
  float* op = out + ((size_t)b * T + (size_t)k * CHUNK) * C + c;
  const int gtid = (blockIdx.x << 8) | threadIdx.x;
  // Dummy sink for warm-up stores (keeps load:store 1:1 for vmcnt math).
  // Fallback: op itself (same-thread same-address stores are ordered; real
  // group 0 rewrites these locations afterwards).
  float* dummy = use_ws ? (ws + gtid) : op;

  float buf[D];
  float Vm = 0.0f;

  // Prologue: 25 loads in flight before any compute.
#pragma unroll
  for (int u = 0; u < D; ++u)
    asm volatile("global_load_dword %0, %1, off"
                 : "=v"(buf[u])
                 : "v"(xp + (size_t)u * C)
                 : "memory");

#pragma unroll 1
  for (int g = 0; g < ng - 1; ++g) {   // groups with refill loads
    float* q = (g < nwg) ? dummy : (op + (size_t)(g - nwg) * D * C);
    const float* pn = xp + (size_t)(g + 1) * D * C;
#pragma unroll
    for (int u = 0; u < D; ++u) {
      asm volatile("s_waitcnt vmcnt(24)" ::: "memory");
      __builtin_amdgcn_sched_barrier(0);
      float dv = decay * Vm;               // one rounding, no FMA
      dv = (Vm < 1.0f) ? dv : 0.0f;        // hard-reset gate
      float s = buf[u] + dv;               // one rounding
      Vm = fmaxf(s, 0.0f);                 // relu
      __builtin_nontemporal_store((Vm > 1.0f) ? 1.0f : 0.0f,
                                  q + (size_t)u * C);
      asm volatile("global_load_dword %0, %1, off"
                   : "=v"(buf[u])
                   : "v"(pn + (size_t)u * C)
                   : "memory");
    }
  }

  {  // last group: consume remaining 25, no refills
    float* q = op + (size_t)(ng - 1 - nwg) * D * C;
#pragma unroll
    for (int u = 0; u < D; ++u) {
      asm volatile("s_waitcnt vmcnt(24)" ::: "memory");
      __builtin_amdgcn_sched_barrier(0);
      float dv = decay * Vm;
      dv = (Vm < 1.0f) ? dv : 0.0f;
      float s = buf[u] + dv;
      Vm = fmaxf(s, 0.0f);
      __builtin_nontemporal_store((Vm > 1.0f) ? 1.0f : 0.0f,
                                  q + (size_t)u * C);
    }
  }
}

extern "C" void kernel_launch(void* const* d_in, const int* in_sizes, int n_in,
                              void* d_out, int out_size, void* d_ws, size_t ws_size,
                              hipStream_t stream) {
  const float* x = (const float*)d_in[0];
  const float* w = (const float*)d_in[1];
  float* out = (float*)d_out;
  int use_ws = (ws_size >= (size_t)(2u << 20)) ? 1 : 0;
  dim3 block(256);
  dim3 grid((B * C) / 256 * NCH);   // 1024 blocks: chunk = bid>>8
  lif_kernel<<<grid, block, 0, stream>>>(x, w, out, (float*)d_ws, use_ws);
}